// Round 2
// baseline (182.796 us; speedup 1.0000x reference)
//
#include <hip/hip_runtime.h>
#include <hip/hip_cooperative_groups.h>

namespace cg = cooperative_groups;

#define BB 8
#define TT 2048
#define DD 128
#define CH 32              // k-chunks (64 rows each): 32*8 = 256 blocks (full GPU)
#define GT_STRIDE 72       // bf16 elems per Gt row (64 + 8 pad)

typedef __attribute__((ext_vector_type(8))) short bf16x8;
typedef __attribute__((ext_vector_type(4))) float f32x4;
typedef unsigned short u16;

static __device__ __forceinline__ float bf2f(u16 u) {
    union { unsigned int i; float f; } v; v.i = ((unsigned int)u) << 16; return v.f;
}
static __device__ __forceinline__ u16 f2bf(float f) {
    union { float f; unsigned int i; } v; v.f = f;
    unsigned int x = v.i;
    return (u16)((x + 0x7FFFu + ((x >> 16) & 1u)) >> 16);  // RNE
}

// ===========================================================================
// Single cooperative kernel, 256 blocks x 256 threads, 1 block/CU.
// Phase 1: P[chunk][b] = enc_chunk^T @ enc_chunk (64-row chunk, K=64, bf16
//          MFMA through the 18 KB LDS transpose). Identical math to R1.
// Phase 2: Gw[b] = sum_c P[c][b] (element-wise, deterministic order, bf16).
// Phase 3: out[b] = dec[b] @ G[b] (A-frags direct from global, Gs staged raw).
// Frag-keyed P/G layout throughout (HW-verified in earlier rounds): within
// each 16x16 tile, producing lane (q,ln) stores its 4 C-regs at elem offset
// ln*16 + (q>>1)*8 + (q&1)*4, so phase-3 B-frag = one ds_read_b128.
// grid.sync() + __threadfence() give cross-XCD visibility of P and Gw.
// ===========================================================================
__global__ __launch_bounds__(256, 1) void fused_luong(const float* __restrict__ enc,
                                                      const float* __restrict__ dec,
                                                      u16* __restrict__ P,
                                                      u16* __restrict__ Gw,
                                                      float* __restrict__ out) {
    const int bid  = blockIdx.x;           // 0..255
    const int t    = threadIdx.x;
    const int wave = t >> 6, lane = t & 63, quad = lane >> 4, ln = lane & 15;
    const int chunk = bid & (CH - 1);      // 0..31
    const int b     = bid >> 5;            // 0..7

    __shared__ __align__(16) u16 smem[DD * DD];   // 32 KB; phase 1 uses first 18 KB

    // ---------------- Phase 1: partial Gram ----------------
    {
        const int d  = t & 127;
        const int kh = t >> 7;             // 0..1

        f32x4 acc[2][8];
        #pragma unroll
        for (int mi = 0; mi < 2; ++mi)
            #pragma unroll
            for (int nt = 0; nt < 8; ++nt) acc[mi][nt] = (f32x4){0.f, 0.f, 0.f, 0.f};

        const float* src = enc + ((size_t)b * TT + (size_t)chunk * 64) * DD;
        #pragma unroll
        for (int a = 0; a < 8; ++a) {
            const int k4 = a * 2 + kh;     // 0..15 -> rows k4*4+i cover 0..63
            u16 o[4];
            #pragma unroll
            for (int i = 0; i < 4; ++i)
                o[i] = f2bf(src[(k4 * 4 + i) * DD + d]);
            *(ushort4*)&smem[d * GT_STRIDE + k4 * 4] = *(const ushort4*)o;
        }
        __syncthreads();

        bf16x8 afrag[2][2];
        #pragma unroll
        for (int mi = 0; mi < 2; ++mi)
            #pragma unroll
            for (int ks = 0; ks < 2; ++ks)
                afrag[mi][ks] = *(const bf16x8*)&smem[((wave * 2 + mi) * 16 + ln) * GT_STRIDE
                                                      + ks * 32 + quad * 8];
        #pragma unroll
        for (int ks = 0; ks < 2; ++ks) {
            #pragma unroll
            for (int nt = 0; nt < 8; ++nt) {
                const bf16x8 bfrag = *(const bf16x8*)&smem[(nt * 16 + ln) * GT_STRIDE
                                                           + ks * 32 + quad * 8];
                #pragma unroll
                for (int mi = 0; mi < 2; ++mi)
                    acc[mi][nt] = __builtin_amdgcn_mfma_f32_16x16x32_bf16(
                        afrag[mi][ks], bfrag, acc[mi][nt], 0, 0, 0);
            }
        }

        // Epilogue: frag-keyed layout, 512B contiguous per tile.
        u16* Pb = P + ((size_t)chunk * BB + b) * (DD * DD);
        const int off = ln * 16 + (quad >> 1) * 8 + (quad & 1) * 4;
        #pragma unroll
        for (int mi = 0; mi < 2; ++mi) {
            #pragma unroll
            for (int nt = 0; nt < 8; ++nt) {
                u16 o[4];
                #pragma unroll
                for (int r = 0; r < 4; ++r) o[r] = f2bf(acc[mi][nt][r]);
                const int tile = (wave * 2 + mi) * 8 + nt;
                *(ushort4*)&Pb[tile * 256 + off] = *(const ushort4*)o;
            }
        }
    }

    __threadfence();                       // device-scope release of P (cross-XCD)
    cg::this_grid().sync();

    // ---------------- Phase 2: reduce over chunks ----------------
    {
        const int g = bid * 256 + t;       // 0..65535; work = 32768 ushort4
        if (g < BB * DD * DD / 4) {
            const ushort4* Pu = (const ushort4*)P;
            const int stride = BB * DD * DD / 4;
            float sx = 0.f, sy = 0.f, sz = 0.f, sw = 0.f;
            #pragma unroll
            for (int c = 0; c < CH; ++c) {
                const ushort4 v = Pu[(size_t)c * stride + g];
                sx += bf2f(v.x); sy += bf2f(v.y); sz += bf2f(v.z); sw += bf2f(v.w);
            }
            ushort4 o; o.x = f2bf(sx); o.y = f2bf(sy); o.z = f2bf(sz); o.w = f2bf(sw);
            ((ushort4*)Gw)[g] = o;
        }
    }

    __threadfence();                       // device-scope release of Gw (cross-XCD)
    cg::this_grid().sync();

    // ---------------- Phase 3: apply out[b] = dec[b] @ G[b] ----------------
    {
        const int qt = wave * 16;

        // Issue dec loads first (independent of LDS) so they overlap Gs staging.
        const float* drow = dec + ((size_t)b * TT + (size_t)chunk * 64 + qt + ln) * DD
                            + quad * 8;
        float4 dv[4][2];
        #pragma unroll
        for (int ks = 0; ks < 4; ++ks) {
            dv[ks][0] = *(const float4*)(drow + ks * 32);
            dv[ks][1] = *(const float4*)(drow + ks * 32 + 4);
        }

        // Stage G[b] raw (frag-keyed layout), coalesced uint4.
        const uint4* gsrc = (const uint4*)(Gw + (size_t)b * DD * DD);
        #pragma unroll
        for (int i = 0; i < 8; ++i)
            ((uint4*)smem)[i * 256 + t] = gsrc[i * 256 + t];

        // Convert A-frags in registers (RNE, identical to staged values).
        bf16x8 afrag[4];
        #pragma unroll
        for (int ks = 0; ks < 4; ++ks) {
            union { u16 o[8]; bf16x8 v; } u;
            u.o[0] = f2bf(dv[ks][0].x); u.o[1] = f2bf(dv[ks][0].y);
            u.o[2] = f2bf(dv[ks][0].z); u.o[3] = f2bf(dv[ks][0].w);
            u.o[4] = f2bf(dv[ks][1].x); u.o[5] = f2bf(dv[ks][1].y);
            u.o[6] = f2bf(dv[ks][1].z); u.o[7] = f2bf(dv[ks][1].w);
            afrag[ks] = u.v;
        }
        __syncthreads();

        f32x4 acc[8];
        #pragma unroll
        for (int dt = 0; dt < 8; ++dt) acc[dt] = (f32x4){0.f, 0.f, 0.f, 0.f};

        #pragma unroll
        for (int ks = 0; ks < 4; ++ks) {
            const int mtk  = ks * 2 + (quad >> 1);
            const int boff = ln * 16 + (quad & 1) * 8;
            #pragma unroll
            for (int dt = 0; dt < 8; ++dt) {
                const bf16x8 bb = *(const bf16x8*)&smem[(mtk * 8 + dt) * 256 + boff];
                acc[dt] = __builtin_amdgcn_mfma_f32_16x16x32_bf16(afrag[ks], bb, acc[dt], 0, 0, 0);
            }
        }

        // Epilogue: C/D layout col=lane&15, row=quad*4+reg (HW-verified).
        float* ob = out + ((size_t)b * TT + (size_t)chunk * 64) * DD;
        #pragma unroll
        for (int dt = 0; dt < 8; ++dt) {
            const int dcol = dt * 16 + ln;
            #pragma unroll
            for (int r = 0; r < 4; ++r) {
                const int q = qt + quad * 4 + r;
                ob[q * DD + dcol] = acc[dt][r];
            }
        }
    }
}

extern "C" void kernel_launch(void* const* d_in, const int* in_sizes, int n_in,
                              void* d_out, int out_size, void* d_ws, size_t ws_size,
                              hipStream_t stream) {
    const float* enc = (const float*)d_in[0];  // (8,2048,128) fp32
    const float* dec = (const float*)d_in[1];  // (8,2048,128) fp32
    float* out = (float*)d_out;                // (8,2048,128) fp32

    // ws: P bf16 partials (CH * 256 KB = 8 MB) | Gw bf16 (256 KB)
    u16* P  = (u16*)d_ws;
    u16* Gw = (u16*)((char*)d_ws + (size_t)CH * BB * DD * DD * sizeof(u16));

    void* args[] = {(void*)&enc, (void*)&dec, (void*)&P, (void*)&Gw, (void*)&out};
    hipLaunchCooperativeKernel((void*)fused_luong, dim3(CH * BB), dim3(256),
                               args, 0, stream);
}

// Round 3
// 165.309 us; speedup vs baseline: 1.1058x; 1.1058x over previous
//
#include <hip/hip_runtime.h>

#define BB 8
#define TT 2048
#define DD 128
#define NCH 32             // k-chunks of 64 rows covering K=2048
#define GT_STRIDE 72       // bf16 elems per Gt row (64 + 8 pad)

typedef __attribute__((ext_vector_type(8))) short bf16x8;
typedef __attribute__((ext_vector_type(4))) float f32x4;
typedef unsigned short u16;

static __device__ __forceinline__ u16 f2bf(float f) {
    union { float f; unsigned int i; } v; v.f = f;
    unsigned int x = v.i;
    return (u16)((x + 0x7FFFu + ((x >> 16) & 1u)) >> 16);  // RNE
}

// ===========================================================================
// ONE kernel, 256 blocks x 256 threads, no inter-block sync, no workspace.
// Each block (b, chunk) redundantly computes the FULL Gram G[b] = enc_b^T@enc_b
// (fp32 MFMA accum over all 32 k-chunks through the proven LDS-transpose),
// rounds it ONCE to bf16 into LDS (frag-keyed layout), then applies its own
// 64 dec rows: out = dec_chunk @ G.  Redundancy (32x Gram) trades ~17 GFLOP
// (~7 us at peak, L2-fed) for the ~25-30 us of launch boundaries + P traffic
// the 3-kernel pipeline paid.
//
// b = bid & 7: consecutive blockIdx round-robin across the 8 XCDs, so all 32
// same-b blocks land on one XCD and enc[b] (1 MB) stays L2-resident there.
//
// Double-buffered Gt => ONE barrier per k-chunk (write cur; sync; read cur —
// prior-iter reads complete at the barrier, next-iter writes go to the other
// buffer, re-writes of this buffer are two barriers away).
//
// Frag-keyed G layout + all fragment/epilogue mappings are byte-identical to
// the HW-verified R1 kernels.
// ===========================================================================
__global__ __launch_bounds__(256, 1) void luong_fused(const float* __restrict__ enc,
                                                      const float* __restrict__ dec,
                                                      float* __restrict__ out) {
    const int bid   = blockIdx.x;          // 0..255
    const int b     = bid & 7;             // XCD-local batch
    const int chunk = bid >> 3;            // 0..31 q-chunk (64 dec rows)
    const int t     = threadIdx.x;
    const int wave  = t >> 6, lane = t & 63, quad = lane >> 4, ln = lane & 15;

    __shared__ __align__(16) u16 Gt[2][DD * GT_STRIDE];  // 2 x 18 KB transpose buf
    __shared__ __align__(16) u16 Gs[DD * DD];            // 32 KB, frag-keyed G

    // ---- Early dec loads (independent of everything), convert to A-frags ----
    const int qt = wave * 16;
    const float* drow = dec + ((size_t)b * TT + (size_t)chunk * 64 + qt + ln) * DD
                        + quad * 8;
    bf16x8 afrag[4];
    #pragma unroll
    for (int ks = 0; ks < 4; ++ks) {
        const float4 d0 = *(const float4*)(drow + ks * 32);
        const float4 d1 = *(const float4*)(drow + ks * 32 + 4);
        union { u16 o[8]; bf16x8 v; } u;
        u.o[0] = f2bf(d0.x); u.o[1] = f2bf(d0.y); u.o[2] = f2bf(d0.z); u.o[3] = f2bf(d0.w);
        u.o[4] = f2bf(d1.x); u.o[5] = f2bf(d1.y); u.o[6] = f2bf(d1.z); u.o[7] = f2bf(d1.w);
        afrag[ks] = u.v;
    }

    // ---- Gram: G[b] = enc_b^T @ enc_b, fp32 accum over 32 k-chunks ----
    const int d  = t & 127;
    const int kh = t >> 7;                 // 0..1

    f32x4 acc[2][8];
    #pragma unroll
    for (int mi = 0; mi < 2; ++mi)
        #pragma unroll
        for (int nt = 0; nt < 8; ++nt) acc[mi][nt] = (f32x4){0.f, 0.f, 0.f, 0.f};

    for (int kc = 0; kc < NCH; ++kc) {
        u16* gt = Gt[kc & 1];
        const float* src = enc + ((size_t)b * TT + (size_t)kc * 64) * DD;
        #pragma unroll
        for (int a = 0; a < 8; ++a) {
            const int k4 = a * 2 + kh;     // 0..15 -> rows k4*4+i cover 0..63
            u16 o[4];
            #pragma unroll
            for (int i = 0; i < 4; ++i)
                o[i] = f2bf(src[(k4 * 4 + i) * DD + d]);
            *(ushort4*)&gt[d * GT_STRIDE + k4 * 4] = *(const ushort4*)o;
        }
        __syncthreads();

        bf16x8 ga[2][2];
        #pragma unroll
        for (int mi = 0; mi < 2; ++mi)
            #pragma unroll
            for (int ks = 0; ks < 2; ++ks)
                ga[mi][ks] = *(const bf16x8*)&gt[((wave * 2 + mi) * 16 + ln) * GT_STRIDE
                                                 + ks * 32 + quad * 8];
        #pragma unroll
        for (int ks = 0; ks < 2; ++ks) {
            #pragma unroll
            for (int nt = 0; nt < 8; ++nt) {
                const bf16x8 gb = *(const bf16x8*)&gt[(nt * 16 + ln) * GT_STRIDE
                                                      + ks * 32 + quad * 8];
                #pragma unroll
                for (int mi = 0; mi < 2; ++mi)
                    acc[mi][nt] = __builtin_amdgcn_mfma_f32_16x16x32_bf16(
                        ga[mi][ks], gb, acc[mi][nt], 0, 0, 0);
            }
        }
    }

    // ---- Round G once to bf16, store frag-keyed into Gs (ds_write_b64) ----
    const int off = ln * 16 + (quad >> 1) * 8 + (quad & 1) * 4;
    #pragma unroll
    for (int mi = 0; mi < 2; ++mi) {
        #pragma unroll
        for (int nt = 0; nt < 8; ++nt) {
            u16 o[4];
            #pragma unroll
            for (int r = 0; r < 4; ++r) o[r] = f2bf(acc[mi][nt][r]);
            const int tile = (wave * 2 + mi) * 8 + nt;
            *(ushort4*)&Gs[tile * 256 + off] = *(const ushort4*)o;
        }
    }
    __syncthreads();

    // ---- Apply: out_chunk = dec_chunk @ G ----
    f32x4 oacc[8];
    #pragma unroll
    for (int dt = 0; dt < 8; ++dt) oacc[dt] = (f32x4){0.f, 0.f, 0.f, 0.f};

    #pragma unroll
    for (int ks = 0; ks < 4; ++ks) {
        const int mtk  = ks * 2 + (quad >> 1);
        const int boff = ln * 16 + (quad & 1) * 8;
        #pragma unroll
        for (int dt = 0; dt < 8; ++dt) {
            const bf16x8 gb = *(const bf16x8*)&Gs[(mtk * 8 + dt) * 256 + boff];
            oacc[dt] = __builtin_amdgcn_mfma_f32_16x16x32_bf16(afrag[ks], gb, oacc[dt], 0, 0, 0);
        }
    }

    // ---- Epilogue: C/D layout col=lane&15, row=quad*4+reg (HW-verified) ----
    float* ob = out + ((size_t)b * TT + (size_t)chunk * 64) * DD;
    #pragma unroll
    for (int dt = 0; dt < 8; ++dt) {
        const int dcol = dt * 16 + ln;
        #pragma unroll
        for (int r = 0; r < 4; ++r) {
            const int q = qt + quad * 4 + r;
            ob[q * DD + dcol] = oacc[dt][r];
        }
    }
}

extern "C" void kernel_launch(void* const* d_in, const int* in_sizes, int n_in,
                              void* d_out, int out_size, void* d_ws, size_t ws_size,
                              hipStream_t stream) {
    const float* enc = (const float*)d_in[0];  // (8,2048,128) fp32
    const float* dec = (const float*)d_in[1];  // (8,2048,128) fp32
    float* out = (float*)d_out;                // (8,2048,128) fp32
    (void)d_ws; (void)ws_size;                 // no workspace needed

    luong_fused<<<dim3(BB * NCH), 256, 0, stream>>>(enc, dec, out);
}

// Round 4
// 100.794 us; speedup vs baseline: 1.8136x; 1.6401x over previous
//
#include <hip/hip_runtime.h>

#define BB 8
#define TT 2048
#define DD 128
#define NCH 32             // k-chunks of 64 rows covering K=2048

typedef __attribute__((ext_vector_type(8))) short bf16x8;
typedef __attribute__((ext_vector_type(4))) float f32x4;
typedef unsigned short u16;

static __device__ __forceinline__ u16 f2bf(float f) {
    union { float f; unsigned int i; } v; v.f = f;
    unsigned int x = v.i;
    return (u16)((x + 0x7FFFu + ((x >> 16) & 1u)) >> 16);  // RNE
}

// ===========================================================================
// ONE kernel, 256 blocks x 1024 threads (16 waves = 4/SIMD), no workspace
// (ws use costs a timed 41us poison-fill), no inter-block sync.
//
// Block (b, chunk): redundantly computes G[b] = enc_b^T @ enc_b, then applies
// its 64 dec rows. R3's version of this was latency-bound at 1 wave/SIMD
// (MfmaUtil 4.6%, VALUBusy 8.2%, 87% idle). Changes:
//   1. 16 waves: Gram tiles split 16 ways, staging 4 ways -> real TLP.
//   2. Symmetry: only 36 of 64 G-tiles computed (diag tiles use af as both
//      MFMA operands); lower triangle mirrored in LDS. 88 (vs 160) b128/chunk.
//   3. Gt is unpadded [128][64] bf16 with a 16B-slot XOR swizzle
//      (idx ^= (row&7)<<3 in u16 units) -> conflict-free ds_read_b128 /
//      ds_write_b64 (R3's stride-72 layout was ~8-way conflicted, 3.87M).
//
// Frag-keyed Gs layout (HW-verified R1-R3) = column-major within 16x16 tiles:
// elem (row,col) of tile (i,j) at Gs[(i*8+j)*256 + col*16 + row].
// ===========================================================================
__global__ __launch_bounds__(1024, 4) void luong_fused(const float* __restrict__ enc,
                                                       const float* __restrict__ dec,
                                                       float* __restrict__ out) {
    const int bid   = blockIdx.x;          // 0..255
    const int b     = bid & 7;             // XCD-local batch
    const int chunk = bid >> 3;            // 0..31 q-chunk (64 dec rows)
    const int t     = threadIdx.x;
    const int wave  = t >> 6, lane = t & 63, quad = lane >> 4, ln = lane & 15;

    __shared__ __align__(16) u16 Gt[2][DD * 64];   // 2 x 16 KB, swizzled transpose
    __shared__ __align__(16) u16 Gs[DD * DD];      // 32 KB, frag-keyed G

    // ---- Early dec loads (HBM, overlap the whole Gram phase) -> A-frags ----
    const int rowt = wave & 3, dgrp = wave >> 2;
    const float* drow = dec + ((size_t)b * TT + (size_t)chunk * 64 + rowt * 16 + ln) * DD
                        + quad * 8;
    bf16x8 dfrag[4];
    #pragma unroll
    for (int ks = 0; ks < 4; ++ks) {
        const float4 d0 = *(const float4*)(drow + ks * 32);
        const float4 d1 = *(const float4*)(drow + ks * 32 + 4);
        union { u16 o[8]; bf16x8 v; } u;
        u.o[0] = f2bf(d0.x); u.o[1] = f2bf(d0.y); u.o[2] = f2bf(d0.z); u.o[3] = f2bf(d0.w);
        u.o[4] = f2bf(d1.x); u.o[5] = f2bf(d1.y); u.o[6] = f2bf(d1.z); u.o[7] = f2bf(d1.w);
        dfrag[ks] = u.v;
    }

    // ---- Symmetric Gram: wave (mt=w>>1, sub=w&1) owns tiles (mt, nt) with
    //      nt = mt+sub, mt+sub+2, ... < 8  (diag on sub==0, slot 0) ----
    const int mt = wave >> 1, sub = wave & 1;
    const int d  = t & 127, kh = t >> 7;   // staging: column d, k-groups kh*2..+2
    const int xw = (d  & 7) << 3;          // write-side swizzle (u16 units)
    const int xr = (ln & 7) << 3;          // read-side swizzle (row&7 == ln&7)

    f32x4 acc[4];
    #pragma unroll
    for (int s = 0; s < 4; ++s) acc[s] = (f32x4){0.f, 0.f, 0.f, 0.f};

    for (int kc = 0; kc < NCH; ++kc) {
        u16* gt = Gt[kc & 1];
        const float* src = enc + ((size_t)b * TT + (size_t)kc * 64) * DD;
        #pragma unroll
        for (int a = 0; a < 2; ++a) {
            const int k4 = kh * 2 + a;     // 0..15
            u16 o[4];
            #pragma unroll
            for (int i = 0; i < 4; ++i)
                o[i] = f2bf(src[(k4 * 4 + i) * DD + d]);
            *(ushort4*)&gt[(d * 64 + k4 * 4) ^ xw] = *(const ushort4*)o;
        }
        __syncthreads();

        bf16x8 af[2];
        #pragma unroll
        for (int ks = 0; ks < 2; ++ks)
            af[ks] = *(const bf16x8*)&gt[((mt * 16 + ln) * 64 + ks * 32 + quad * 8) ^ xr];

        #pragma unroll
        for (int slot = 0; slot < 4; ++slot) {
            const int nt = mt + sub + slot * 2;
            if (nt < 8) {
                if (slot == 0 && sub == 0) {           // diagonal: B == A
                    #pragma unroll
                    for (int ks = 0; ks < 2; ++ks)
                        acc[0] = __builtin_amdgcn_mfma_f32_16x16x32_bf16(
                            af[ks], af[ks], acc[0], 0, 0, 0);
                } else {
                    #pragma unroll
                    for (int ks = 0; ks < 2; ++ks) {
                        const bf16x8 bf = *(const bf16x8*)
                            &gt[((nt * 16 + ln) * 64 + ks * 32 + quad * 8) ^ xr];
                        acc[slot] = __builtin_amdgcn_mfma_f32_16x16x32_bf16(
                            af[ks], bf, acc[slot], 0, 0, 0);
                    }
                }
            }
        }
    }

    // ---- Round upper+diag tiles to bf16, write frag-keyed into Gs ----
    const int off = ln * 16 + quad * 4;    // column-major within tile
    #pragma unroll
    for (int slot = 0; slot < 4; ++slot) {
        const int nt = mt + sub + slot * 2;
        if (nt < 8) {
            u16 o[4];
            #pragma unroll
            for (int r = 0; r < 4; ++r) o[r] = f2bf(acc[slot][r]);
            *(ushort4*)&Gs[(mt * 8 + nt) * 256 + off] = *(const ushort4*)o;
        }
    }
    __syncthreads();

    // ---- Mirror lower triangle: tile(i,j)[r][c] = tile(j,i)[c][r] ----
    // dst idx = (i*8+j)*256 + c*16 + r ; src = (j*8+i)*256 + r*16 + c.
    // Sources are upper/diag (never written here) -> no intra-pass hazard.
    #pragma unroll
    for (int e = 0; e < 16; ++e) {
        const int idx = e * 1024 + t;
        const int ti = idx >> 8, i = ti >> 3, j = ti & 7;
        if (i > j) {
            const int w = idx & 255, row = w & 15, col = w >> 4;
            Gs[idx] = Gs[(j * 8 + i) * 256 + row * 16 + col];
        }
    }
    __syncthreads();

    // ---- Apply: wave (rowt, dgrp) does 16 dec rows x 32 out cols ----
    f32x4 oacc[2];
    #pragma unroll
    for (int dtl = 0; dtl < 2; ++dtl) oacc[dtl] = (f32x4){0.f, 0.f, 0.f, 0.f};

    #pragma unroll
    for (int ks = 0; ks < 4; ++ks) {
        const int mtk  = ks * 2 + (quad >> 1);
        const int boff = ln * 16 + (quad & 1) * 8;
        #pragma unroll
        for (int dtl = 0; dtl < 2; ++dtl) {
            const int dt = dgrp * 2 + dtl;
            const bf16x8 bbf = *(const bf16x8*)&Gs[(mtk * 8 + dt) * 256 + boff];
            oacc[dtl] = __builtin_amdgcn_mfma_f32_16x16x32_bf16(
                dfrag[ks], bbf, oacc[dtl], 0, 0, 0);
        }
    }

    // ---- Epilogue: C/D layout col=lane&15, row=quad*4+reg (HW-verified) ----
    float* ob = out + ((size_t)b * TT + (size_t)chunk * 64 + rowt * 16) * DD;
    #pragma unroll
    for (int dtl = 0; dtl < 2; ++dtl) {
        const int dcol = (dgrp * 2 + dtl) * 16 + ln;
        #pragma unroll
        for (int r = 0; r < 4; ++r)
            ob[(quad * 4 + r) * DD + dcol] = oacc[dtl][r];
    }
}

extern "C" void kernel_launch(void* const* d_in, const int* in_sizes, int n_in,
                              void* d_out, int out_size, void* d_ws, size_t ws_size,
                              hipStream_t stream) {
    const float* enc = (const float*)d_in[0];  // (8,2048,128) fp32
    const float* dec = (const float*)d_in[1];  // (8,2048,128) fp32
    float* out = (float*)d_out;                // (8,2048,128) fp32
    (void)d_ws; (void)ws_size;                 // ws unused: its poison-fill is timed (+41 us)

    luong_fused<<<dim3(BB * NCH), 1024, 0, stream>>>(enc, dec, out);
}

// Round 5
// 96.147 us; speedup vs baseline: 1.9012x; 1.0483x over previous
//
#include <hip/hip_runtime.h>

#define BB 8
#define TT 2048
#define DD 128
#define NCH 16             // k-chunks of 128 rows covering K=2048

typedef __attribute__((ext_vector_type(8))) short bf16x8;
typedef __attribute__((ext_vector_type(4))) float f32x4;
typedef unsigned short u16;

static __device__ __forceinline__ u16 f2bf(float f) {
    union { float f; unsigned int i; } v; v.f = f;
    unsigned int x = v.i;
    return (u16)((x + 0x7FFFu + ((x >> 16) & 1u)) >> 16);  // RNE
}

// ===========================================================================
// ONE kernel, 256 blocks x 1024 threads, 96 KB LDS (=> exactly 1 block/CU,
// no packing imbalance), no workspace, no inter-block sync.
//
// R4 was LDS-latency/serialization bound (MfmaUtil 7.4%, 47us): 32 barrier-
// coupled chunks with post-barrier L2 loads and 2x-conflicted LDS writes.
// R5 changes:
//   1. 128-row k-chunks (16 iters): half the barrier/latency events.
//   2. Register prefetch: chunk kc+1's 16 enc values are loaded into VGPRs
//      BEFORE the barrier of chunk kc -> L2 latency hides under MFMA phase.
//      Double-buffered Gt keeps ONE barrier per chunk (writes of iter kc+1 go
//      to the buffer last read in iter kc-1, separated by iter kc's barrier).
//   3. 4-bit granule swizzle, same function f(row,g) = row*128 + ((g^(row&15))<<3)
//      for writes and reads: 16B stores hit 16 distinct slots (8cy, optimal),
//      b128 frag reads hit 8 balanced bank-groups (8cy, optimal). Replaces
//      R4's 3-bit XOR (2x write serialization, 1.33M conflict cycles).
//
// Gram tile symmetry, frag-keyed Gs layout, mirror, apply, and epilogue are
// byte-identical to R4 (harness-verified).
// ===========================================================================
__global__ __launch_bounds__(1024, 4) void luong_fused(const float* __restrict__ enc,
                                                       const float* __restrict__ dec,
                                                       float* __restrict__ out) {
    const int bid   = blockIdx.x;          // 0..255
    const int b     = bid & 7;             // XCD-local batch
    const int chunk = bid >> 3;            // 0..31 q-chunk (64 dec rows)
    const int t     = threadIdx.x;
    const int wave  = t >> 6, lane = t & 63, quad = lane >> 4, ln = lane & 15;

    __shared__ __align__(16) u16 Gt[2][DD * DD];   // 2 x 32 KB, swizzled [d][k]
    __shared__ __align__(16) u16 Gs[DD * DD];      // 32 KB, frag-keyed G

    // ---- Early dec loads (HBM, overlap the whole Gram phase) -> A-frags ----
    const int rowt = wave & 3, dgrp = wave >> 2;
    const float* drow = dec + ((size_t)b * TT + (size_t)chunk * 64 + rowt * 16 + ln) * DD
                        + quad * 8;
    bf16x8 dfrag[4];
    #pragma unroll
    for (int ks = 0; ks < 4; ++ks) {
        const float4 d0 = *(const float4*)(drow + ks * 32);
        const float4 d1 = *(const float4*)(drow + ks * 32 + 4);
        union { u16 o[8]; bf16x8 v; } u;
        u.o[0] = f2bf(d0.x); u.o[1] = f2bf(d0.y); u.o[2] = f2bf(d0.z); u.o[3] = f2bf(d0.w);
        u.o[4] = f2bf(d1.x); u.o[5] = f2bf(d1.y); u.o[6] = f2bf(d1.z); u.o[7] = f2bf(d1.w);
        dfrag[ks] = u.v;
    }

    // ---- Gram staging assignment: thread = (d, kg): column d, k = kg*16..+15 ----
    const int d  = t & 127, kg = t >> 7;   // kg 0..7
    const int mt = wave >> 1, sub = wave & 1;

    f32x4 acc[4];
    #pragma unroll
    for (int s = 0; s < 4; ++s) acc[s] = (f32x4){0.f, 0.f, 0.f, 0.f};

    // Prologue: prefetch chunk 0 into registers.
    float pf[16];
    {
        const float* src = enc + (size_t)b * TT * DD;
        #pragma unroll
        for (int i = 0; i < 16; ++i) pf[i] = src[(kg * 16 + i) * DD + d];
    }

    for (int kc = 0; kc < NCH; ++kc) {
        u16* gt = Gt[kc & 1];

        // Convert prefetched chunk, write two swizzled 16B granules.
        union { u16 o[16]; uint4 q[2]; } cv;
        #pragma unroll
        for (int i = 0; i < 16; ++i) cv.o[i] = f2bf(pf[i]);
        #pragma unroll
        for (int j = 0; j < 2; ++j)
            *(uint4*)&gt[d * 128 + (((kg * 2 + j) ^ (d & 15)) << 3)] = cv.q[j];

        // Prefetch next chunk (L2 latency hides under barrier + MFMA phase).
        if (kc + 1 < NCH) {
            const float* src = enc + ((size_t)b * TT + (size_t)(kc + 1) * 128) * DD;
            #pragma unroll
            for (int i = 0; i < 16; ++i) pf[i] = src[(kg * 16 + i) * DD + d];
        }

        __syncthreads();                   // gt staged; single barrier per chunk

        #pragma unroll
        for (int ks = 0; ks < 4; ++ks) {
            const bf16x8 af = *(const bf16x8*)
                &gt[(mt * 16 + ln) * 128 + (((ks * 4 + quad) ^ ln) << 3)];
            #pragma unroll
            for (int slot = 0; slot < 4; ++slot) {
                const int nt = mt + sub + slot * 2;
                if (nt < 8) {
                    if (slot == 0 && sub == 0) {       // diagonal: B == A
                        acc[0] = __builtin_amdgcn_mfma_f32_16x16x32_bf16(
                            af, af, acc[0], 0, 0, 0);
                    } else {
                        const bf16x8 bf = *(const bf16x8*)
                            &gt[(nt * 16 + ln) * 128 + (((ks * 4 + quad) ^ ln) << 3)];
                        acc[slot] = __builtin_amdgcn_mfma_f32_16x16x32_bf16(
                            af, bf, acc[slot], 0, 0, 0);
                    }
                }
            }
        }
        // No trailing barrier: next iter writes the buffer last read in iter
        // kc-1, separated from those reads by THIS iter's barrier.
    }

    // ---- Round upper+diag tiles to bf16, write frag-keyed into Gs ----
    __syncthreads();                       // all MFMA reads of Gt done block-wide
    const int off = ln * 16 + quad * 4;    // column-major within tile
    #pragma unroll
    for (int slot = 0; slot < 4; ++slot) {
        const int nt = mt + sub + slot * 2;
        if (nt < 8) {
            u16 o[4];
            #pragma unroll
            for (int r = 0; r < 4; ++r) o[r] = f2bf(acc[slot][r]);
            *(ushort4*)&Gs[(mt * 8 + nt) * 256 + off] = *(const ushort4*)o;
        }
    }
    __syncthreads();

    // ---- Mirror lower triangle: tile(i,j)[r][c] = tile(j,i)[c][r] ----
    #pragma unroll
    for (int e = 0; e < 16; ++e) {
        const int idx = e * 1024 + t;
        const int ti = idx >> 8, i = ti >> 3, j = ti & 7;
        if (i > j) {
            const int w = idx & 255, row = w & 15, col = w >> 4;
            Gs[idx] = Gs[(j * 8 + i) * 256 + row * 16 + col];
        }
    }
    __syncthreads();

    // ---- Apply: wave (rowt, dgrp) does 16 dec rows x 32 out cols ----
    f32x4 oacc[2];
    #pragma unroll
    for (int dtl = 0; dtl < 2; ++dtl) oacc[dtl] = (f32x4){0.f, 0.f, 0.f, 0.f};

    #pragma unroll
    for (int ks = 0; ks < 4; ++ks) {
        const int mtk  = ks * 2 + (quad >> 1);
        const int boff = ln * 16 + (quad & 1) * 8;
        #pragma unroll
        for (int dtl = 0; dtl < 2; ++dtl) {
            const int dt = dgrp * 2 + dtl;
            const bf16x8 bbf = *(const bf16x8*)&Gs[(mtk * 8 + dt) * 256 + boff];
            oacc[dtl] = __builtin_amdgcn_mfma_f32_16x16x32_bf16(
                dfrag[ks], bbf, oacc[dtl], 0, 0, 0);
        }
    }

    // ---- Epilogue: C/D layout col=lane&15, row=quad*4+reg (HW-verified) ----
    float* ob = out + ((size_t)b * TT + (size_t)chunk * 64 + rowt * 16) * DD;
    #pragma unroll
    for (int dtl = 0; dtl < 2; ++dtl) {
        const int dcol = (dgrp * 2 + dtl) * 16 + ln;
        #pragma unroll
        for (int r = 0; r < 4; ++r)
            ob[(quad * 4 + r) * DD + dcol] = oacc[dtl][r];
    }
}

extern "C" void kernel_launch(void* const* d_in, const int* in_sizes, int n_in,
                              void* d_out, int out_size, void* d_ws, size_t ws_size,
                              hipStream_t stream) {
    const float* enc = (const float*)d_in[0];  // (8,2048,128) fp32
    const float* dec = (const float*)d_in[1];  // (8,2048,128) fp32
    float* out = (float*)d_out;                // (8,2048,128) fp32
    (void)d_ws; (void)ws_size;                 // ws unused: its poison-fill is timed anyway

    luong_fused<<<dim3(BB * NCH * 2), 1024, 0, stream>>>(enc, dec, out);
}